// Round 1
// baseline (112.361 us; speedup 1.0000x reference)
//
#include <hip/hip_runtime.h>
#include <math.h>

#define A_N 5
#define NC 20
#define FD 38
#define SD (FD*FD)        // 1444
#define BD 32
#define OD 50
#define SA (SD*A_N)       // 7220
#define NT 1024           // threads per block (one block per batch)
#define CHUNK 4           // 4*1024 = 4096 strand-A positions; strand B = +4096
#define IGN_T 0.6f
#define OBJ_S 5.0f

__device__ __forceinline__ float sigm(float x) { return 1.0f / (1.0f + __expf(-x)); }

// One block per batch. No workspace: n_pos is resolved block-locally, the
// responsible-object pass runs on wave 0 of the same block, and each block
// atomicAdds its (already n_pos-resolved) contribution into out[0], which a
// 4-byte memset node zeroes first. The inner math is copied verbatim from the
// previous passing kernel (threshold-test: m >= 0.6  <=>  fma(1.6,in,-(e+f6)) >= 0).
__global__ __launch_bounds__(NT) void k_all(
    const float* __restrict__ outputs, const float* __restrict__ targets,
    const float* __restrict__ anchors, float* __restrict__ out)
{
    __shared__ float4 g_box[OD];          // (tlx, tly, brx, bry), ballot-compacted
    __shared__ float  g_e6[OD];           // 0.6*(area+1e-12)  (pos path)
    __shared__ float  g_den[OD];          // area+1e-12        (resp path)
    __shared__ float  s_anc[2 * A_N];
    __shared__ int    s_key[OD];
    __shared__ int    s_cnt, s_any;
    __shared__ float  wb[NT/64], wc[NT/64];

    const int b   = blockIdx.x;
    const int tid = threadIdx.x;
    if (tid == 0) { s_any = 0; s_cnt = 0; }
    if (tid < 2 * A_N) s_anc[tid] = anchors[tid];

    // ---- GT staging + responsible-anchor key: wave 0 only ------------------
    float gx = 0, gy = 0, gw = 0, gh = 0;
    int key = -1, ct = 0;
    if (tid < 64) {
        bool v = false;
        float gtlx = 0, gtly = 0, gbrx = 0, gbry = 0, den = 0;
        if (tid < OD) {
            const float* t = targets + (b * OD + tid) * 5;
            float tx = t[0], ty = t[1], tw = t[2], th = t[3], tc = t[4];
            if (tx + ty + tw + th + tc > 0.0f) {
                v = true;
                gx = tx * FD; gy = ty * FD; gw = tw * FD; gh = th * FD;
                gtlx = gx - gw*0.5f; gtly = gy - gh*0.5f;
                gbrx = gx + gw*0.5f; gbry = gy + gh*0.5f;
                den  = gw * gh + 1e-12f;
                // responsible anchor at the top-left cell (global anchors: avoids
                // an intra-wave LDS write->read ordering dependence on s_anc)
                int cx = (int)floorf(gtlx), cy = (int)floorf(gtly);
                int cell = min(max(cy * FD + cx, 0), SD - 1);
                int ci = cell / FD, cj = cell - ci * FD;
                float acx = (float)cj + 0.5f, acy = (float)ci + 0.5f;
                float areaB = gw * gh;
                float best = -1.0f; int bi = 0;
                for (int a = 0; a < A_N; ++a) {
                    float aw = anchors[2*a] * FD, ah = anchors[2*a+1] * FD;
                    float w = fmaxf(fminf(acx + aw*0.5f, gbrx) - fmaxf(acx - aw*0.5f, gtlx), 0.0f);
                    float h = fmaxf(fminf(acy + ah*0.5f, gbry) - fmaxf(acy - ah*0.5f, gtly), 0.0f);
                    float inter = w * h;
                    float iou = inter / (aw*ah + areaB - inter + 1e-12f);
                    if (iou > best) { best = iou; bi = a; }
                }
                key = bi * SD + cell;
                ct  = (int)tc;
            }
        }
        unsigned long long bal = __ballot(v);
        if (v) {
            int k = __popcll(bal & ((1ull << tid) - 1ull));   // stable compaction
            g_box[k] = make_float4(gtlx, gtly, gbrx, gbry);
            g_e6[k]  = IGN_T * den;
            g_den[k] = den;
        }
        if (tid == 0) s_cnt = __popcll(bal);
        if (tid < OD) s_key[tid] = key;
    }
    __syncthreads();
    const int cnt = s_cnt;

    float base = 0.0f, corr = 0.0f;
    bool  hot  = false;

    // ---- responsible-object terms: wave 0 winners (runs while waves 1..15
    //      already stream through the position loop) --------------------------
    if (tid < OD && key >= 0) {
        int win = -1;                       // last duplicate wins == numpy .at[].set
        #pragma unroll 10
        for (int o = 0; o < OD; ++o) win = (s_key[o] == key) ? o : win;
        if (win == tid) {
            int a = key / SD, cell = key - a * SD;
            int ci = cell / FD, cj = cell - ci * FD;
            const float* ob = outputs + ((size_t)b * (A_N * 25) + a * 25) * SD + cell;
            float o0 = ob[0], o1 = ob[SD], o2 = ob[2*SD], o3 = ob[3*SD], o4 = ob[4*SD];
            float aw = s_anc[2*a] * FD, ah = s_anc[2*a+1] * FD;
            float px = sigm(o0) + (float)cj;
            float py = sigm(o1) + (float)ci;
            float ew = __expf(o2), eh = __expf(o3);
            float pw = ew * aw, ph = eh * ah;
            float tlx = px - pw*0.5f, tly = py - ph*0.5f;
            float brx = px + pw*0.5f, bry = py + ph*0.5f;
            float ar = pw * ph;
            float bn = 0.0f, bd = 1.0f;
            for (int o = 0; o < cnt; ++o) {
                float4 bx = g_box[o];
                float w = fmaxf(fminf(brx, bx.z) - fmaxf(tlx, bx.x), 0.0f);
                float h = fmaxf(fminf(bry, bx.w) - fmaxf(tly, bx.y), 0.0f);
                float in = w * h, de = ar + g_den[o] - in;
                if (in * bd > bn * de) { bn = in; bd = de; }
            }
            float mi = bn / bd;
            float conf = sigm(o4);
            float d = conf - mi;                   // iou loss, mask=OBJ_SCALE
            base += OBJ_S * OBJ_S * d * d;
            float c2 = conf * conf;                // undo pos-pass noobj term
            if (bn >= IGN_T * bd) corr -= c2;
            else                  base -= c2;
            // box loss: pd = [sigm, sigm, exp, exp] (NO anchor scale on pd)
            float dx = gx - ((float)cj + 0.5f);
            float dy = gy - ((float)ci + 0.5f);
            float e0 = sigm(o0) - dx;
            float e1 = sigm(o1) - dy;
            float e2 = ew - gw / aw;
            float e3 = eh - gh / ah;
            base += e0*e0 + e1*e1 + e2*e2 + e3*e3;
            // class loss: ce = -log_softmax(softmax(x))[ct]; pmax == 1/esum.
            const float* cb = ob + 5 * SD;
            float xmax = -INFINITY;
            #pragma unroll
            for (int k = 0; k < NC; ++k) xmax = fmaxf(xmax, cb[k * SD]);
            float esum = 0.0f;
            #pragma unroll
            for (int k = 0; k < NC; ++k) esum += __expf(cb[k * SD] - xmax);
            float inv = 1.0f / esum;
            float pmax = inv;
            float pct = __expf(cb[ct * SD] - xmax) * inv;
            float e2s = 0.0f;
            #pragma unroll
            for (int k = 0; k < NC; ++k)
                e2s += __expf(__expf(cb[k * SD] - xmax) * inv - pmax);
            base += -(pct - (pmax + __logf(e2s)));
        }
    }

    // ---- position loop: all 1024 threads, dual-strand for ILP ---------------
    for (int c = 0; c < CHUNK; ++c) {
        const int p0 = c * NT + tid;                 // [0, 4096) — always active
        const bool act1 = (p0 + CHUNK * NT < SA);
        const int p1 = act1 ? (p0 + CHUNK * NT) : (SA - 1);  // valid addr always
        int a0 = p0 / SD, r0 = p0 - a0 * SD;
        int a1 = p1 / SD, r1 = p1 - a1 * SD;
        int ii0 = r0 / FD, jj0 = r0 - ii0 * FD;
        int ii1 = r1 / FD, jj1 = r1 - ii1 * FD;
        const float* ob0 = outputs + ((size_t)b * (A_N * 25) + a0 * 25) * SD + r0;
        const float* ob1 = outputs + ((size_t)b * (A_N * 25) + a1 * 25) * SD + r1;
        float q00 = ob0[0], q01 = ob0[SD], q02 = ob0[2*SD], q03 = ob0[3*SD], q04 = ob0[4*SD];
        float q10 = ob1[0], q11 = ob1[SD], q12 = ob1[2*SD], q13 = ob1[3*SD], q14 = ob1[4*SD];

        float aw0 = s_anc[2*a0] * FD, ah0 = s_anc[2*a0+1] * FD;
        float aw1 = s_anc[2*a1] * FD, ah1 = s_anc[2*a1+1] * FD;
        float px0 = sigm(q00) + (float)jj0, py0 = sigm(q01) + (float)ii0;
        float px1 = sigm(q10) + (float)jj1, py1 = sigm(q11) + (float)ii1;
        float pw0 = __expf(q02) * aw0, ph0 = __expf(q03) * ah0;
        float pw1 = __expf(q12) * aw1, ph1 = __expf(q13) * ah1;
        float tlx0 = px0 - pw0*0.5f, tly0 = py0 - ph0*0.5f;
        float brx0 = px0 + pw0*0.5f, bry0 = py0 + ph0*0.5f;
        float tlx1 = px1 - pw1*0.5f, tly1 = py1 - ph1*0.5f;
        float brx1 = px1 + pw1*0.5f, bry1 = py1 + ph1*0.5f;
        float f60 = IGN_T * (pw0 * ph0);
        float f61 = IGN_T * (pw1 * ph1);

        float dm0 = -1e30f, dm1 = -1e30f;
        for (int o = 0; o < cnt; ++o) {
            float4 bx = g_box[o];
            float e = g_e6[o];
            float w0 = fmaxf(fminf(brx0, bx.z) - fmaxf(tlx0, bx.x), 0.0f);
            float h0 = fmaxf(fminf(bry0, bx.w) - fmaxf(tly0, bx.y), 0.0f);
            dm0 = fmaxf(dm0, fmaf((1.0f + IGN_T), w0 * h0, -(e + f60)));
            float w1 = fmaxf(fminf(brx1, bx.z) - fmaxf(tlx1, bx.x), 0.0f);
            float h1 = fmaxf(fminf(bry1, bx.w) - fmaxf(tly1, bx.y), 0.0f);
            dm1 = fmaxf(dm1, fmaf((1.0f + IGN_T), w1 * h1, -(e + f61)));
        }
        float c0 = sigm(q04); c0 *= c0;
        float c1 = sigm(q14); c1 *= c1;
        hot = hot || (dm0 > 0.0f) || (act1 && (dm1 > 0.0f));   // m > 0.6 (n_pos)
        if (dm0 >= 0.0f) corr += c0; else base += c0;          // m >= 0.6
        if (act1) { if (dm1 >= 0.0f) corr += c1; else base += c1; }
    }

    // ---- block reduce + n_pos resolution + single atomic --------------------
    unsigned long long hb = __ballot(hot);
    if ((tid & 63) == 0 && hb) atomicOr(&s_any, 1);
    #pragma unroll
    for (int off = 32; off > 0; off >>= 1) {
        base += __shfl_down(base, off);
        corr += __shfl_down(corr, off);
    }
    const int lane = tid & 63, wv = tid >> 6;
    if (lane == 0) { wb[wv] = base; wc[wv] = corr; }
    __syncthreads();
    if (tid == 0) {
        float sb = 0.0f, sc = 0.0f;
        #pragma unroll
        for (int i = 0; i < NT/64; ++i) { sb += wb[i]; sc += wc[i]; }
        float contrib = sb + (s_any ? 0.0f : sc);
        atomicAdd(out, contrib * (1.0f / (float)BD));
    }
}

extern "C" void kernel_launch(void* const* d_in, const int* in_sizes, int n_in,
                              void* d_out, int out_size, void* d_ws, size_t ws_size,
                              hipStream_t stream) {
    (void)in_sizes; (void)n_in; (void)out_size; (void)d_ws; (void)ws_size;
    // Workspace is deliberately UNUSED: its 256 MiB per-iteration re-poison
    // (fillBufferAligned, ~44 us) dominated the previous timed region.
    hipMemsetAsync(d_out, 0, sizeof(float), stream);
    k_all<<<dim3(BD), NT, 0, stream>>>((const float*)d_in[0],
                                       (const float*)d_in[1],
                                       (const float*)d_in[2],
                                       (float*)d_out);
}

// Round 2
// 96.078 us; speedup vs baseline: 1.1695x; 1.1695x over previous
//
#include <hip/hip_runtime.h>
#include <math.h>

#define A_N 5
#define NC 20
#define FD 38
#define SD (FD*FD)        // 1444
#define BD 32
#define OD 50
#define SA (SD*A_N)       // 7220
#define HALF (SA/2)       // 3610 — each pos-thread does p and p+HALF
#define GXP 15            // pos blocks per batch (15*256 = 3840 >= 3610)
#define IGN_T 0.6f
#define OBJ_S 5.0f

__device__ __forceinline__ float sigm(float x) { return 1.0f / (1.0f + __expf(-x)); }

// Module-scope scratch (zero-initialized at load; self-cleaning per launch).
// All cross-block communication is via device-scope atomics — no reliance on
// plain-store visibility across XCDs, no dispatch-order assumptions.
__device__ float d_pbase[BD];
__device__ float d_pcorr[BD];
__device__ int   d_pflag[BD];
__device__ int   d_pdone[BD];
__device__ float d_total;
__device__ int   d_done;

// grid (GXP+1, BD), 256 threads. blockIdx.x < GXP: noobj/ignore position pass,
// 2 positions/thread (dual-strand ILP). The loop only THRESHOLD-TESTS IoU:
//   m >= 0.6  <=>  dmax >= 0  where dmax = max_o fma(1.6, inter, -(e + 0.6*ar)).
// blockIdx.x == GXP: responsible-object terms. Speculative n_pos split: base
// always counts; corr counts iff n_pos==0 — resolved by the LAST block of the
// batch via d_pdone; the globally-last block writes out[0].
__global__ __launch_bounds__(256) void k_main(
    const float* __restrict__ outputs, const float* __restrict__ targets,
    const float* __restrict__ anchors, float* __restrict__ out)
{
    __shared__ float4 g_box[OD];              // (tlx, tly, brx, bry)
    __shared__ float  g_e[OD];                // pos: 0.6*(area+1e-12); resp: area+1e-12
    __shared__ float  s_anc[2 * A_N];
    __shared__ int    s_cnt, s_any;
    __shared__ int    s_key[OD];
    __shared__ float  wb[4], wc[4];

    const int b = blockIdx.y;
    const int tid = threadIdx.x;
    if (tid == 0) s_any = 0;
    if (tid < 2 * A_N) s_anc[tid] = anchors[tid];

    float blkBase = 0.0f, blkCorr = 0.0f;
    int   blkHot  = 0;

    if (blockIdx.x == GXP) {
        // ---- responsible-object block (1 per batch) ----
        if (tid == 0) s_cnt = 0;
        __syncthreads();
        float gx = 0, gy = 0, gw = 0, gh = 0;
        int ct = 0, key = -1;
        if (tid < OD) {
            const float* t = targets + (b * OD + tid) * 5;
            float tx = t[0], ty = t[1], tw = t[2], th = t[3], tc = t[4];
            if (tx + ty + tw + th + tc > 0.0f) {
                gx = tx * FD; gy = ty * FD; gw = tw * FD; gh = th * FD;
                float gtlx = gx - gw*0.5f, gtly = gy - gh*0.5f;
                float gbrx = gx + gw*0.5f, gbry = gy + gh*0.5f;
                int k = atomicAdd(&s_cnt, 1);
                g_box[k] = make_float4(gtlx, gtly, gbrx, gbry);
                g_e[k] = gw * gh + 1e-12f;     // plain den (resp path)
                int cx = (int)floorf(gtlx), cy = (int)floorf(gtly);
                int cell = min(max(cy * FD + cx, 0), SD - 1);
                int ci = cell / FD, cj = cell - ci * FD;
                float acx = (float)cj + 0.5f, acy = (float)ci + 0.5f;
                float areaB = gw * gh;
                float best = -1.0f; int bi = 0;
                for (int a = 0; a < A_N; ++a) {
                    float aw = s_anc[2*a] * FD, ah = s_anc[2*a+1] * FD;
                    float w = fmaxf(fminf(acx + aw*0.5f, gbrx) - fmaxf(acx - aw*0.5f, gtlx), 0.0f);
                    float h = fmaxf(fminf(acy + ah*0.5f, gbry) - fmaxf(acy - ah*0.5f, gtly), 0.0f);
                    float inter = w * h;
                    float iou = inter / (aw*ah + areaB - inter + 1e-12f);
                    if (iou > best) { best = iou; bi = a; }
                }
                key = bi * SD + cell;
                ct = (int)tc;
            }
        }
        if (tid < OD) s_key[tid] = key;
        __syncthreads();
        const int cnt = s_cnt;

        float rbase = 0.0f, rcorr = 0.0f;
        if (tid < OD && key >= 0) {
            int win = -1;                      // last duplicate wins == numpy
            #pragma unroll 10
            for (int o = 0; o < OD; ++o) win = (s_key[o] == key) ? o : win;
            if (win == tid) {
                int a = key / SD, cell = key - a * SD;
                int ci = cell / FD, cj = cell - ci * FD;
                const float* ob = outputs + ((size_t)b * (A_N * 25) + a * 25) * SD + cell;
                float o0 = ob[0], o1 = ob[SD], o2 = ob[2*SD], o3 = ob[3*SD], o4 = ob[4*SD];
                float aw = s_anc[2*a] * FD, ah = s_anc[2*a+1] * FD;
                float px = sigm(o0) + (float)cj;
                float py = sigm(o1) + (float)ci;
                float ew = __expf(o2), eh = __expf(o3);
                float pw = ew * aw, ph = eh * ah;
                float tlx = px - pw*0.5f, tly = py - ph*0.5f;
                float brx = px + pw*0.5f, bry = py + ph*0.5f;
                float ar = pw * ph;
                float bn = 0.0f, bd = 1.0f;
                for (int o = 0; o < cnt; ++o) {
                    float4 bx = g_box[o];
                    float w = fmaxf(fminf(brx, bx.z) - fmaxf(tlx, bx.x), 0.0f);
                    float h = fmaxf(fminf(bry, bx.w) - fmaxf(tly, bx.y), 0.0f);
                    float in = w * h, de = ar + g_e[o] - in;
                    if (in * bd > bn * de) { bn = in; bd = de; }
                }
                float mi = bn / bd;
                float conf = sigm(o4);
                float d = conf - mi;                   // iou loss, mask=OBJ_SCALE
                rbase += OBJ_S * OBJ_S * d * d;
                float c2 = conf * conf;                // undo pos-block noobj term
                if (bn >= IGN_T * bd) rcorr -= c2;
                else                  rbase -= c2;
                // box loss: pd = [sigm, sigm, exp, exp] (NO anchor scale on pd)
                float dx = gx - ((float)cj + 0.5f);
                float dy = gy - ((float)ci + 0.5f);
                float e0 = sigm(o0) - dx;
                float e1 = sigm(o1) - dy;
                float e2 = ew - gw / aw;
                float e3 = eh - gh / ah;
                rbase += e0*e0 + e1*e1 + e2*e2 + e3*e3;
                // class loss: ce = -log_softmax(softmax(x))[ct], register-lean.
                // pmax == 1/esum algebraically (bit-identical).
                const float* cb = ob + 5 * SD;
                float xmax = -INFINITY;
                #pragma unroll
                for (int k = 0; k < NC; ++k) xmax = fmaxf(xmax, cb[k * SD]);
                float esum = 0.0f;
                #pragma unroll
                for (int k = 0; k < NC; ++k) esum += __expf(cb[k * SD] - xmax);
                float inv = 1.0f / esum;
                float pmax = inv;
                float pct = __expf(cb[ct * SD] - xmax) * inv;
                float e2s = 0.0f;
                #pragma unroll
                for (int k = 0; k < NC; ++k)
                    e2s += __expf(__expf(cb[k * SD] - xmax) * inv - pmax);
                rbase += -(pct - (pmax + __logf(e2s)));
            }
        }
        #pragma unroll
        for (int off = 32; off > 0; off >>= 1) {
            rbase += __shfl_down(rbase, off);
            rcorr += __shfl_down(rcorr, off);
        }
        int lane = tid & 63, w = tid >> 6;
        if (lane == 0) { wb[w] = rbase; wc[w] = rcorr; }
        __syncthreads();
        blkBase = wb[0] + wb[1] + wb[2] + wb[3];
        blkCorr = wc[0] + wc[1] + wc[2] + wc[3];
        blkHot  = 0;
    } else {
        // ---- position blocks: dual-strand, threshold-test loop ----
        const int ix = blockIdx.x * 256 + tid;
        const bool act = (ix < HALF);
        const int p0 = ix, p1 = ix + HALF;
        int a0 = p0 / SD, r0 = p0 - a0 * SD;
        int a1 = p1 / SD, r1 = p1 - a1 * SD;
        int ii0 = r0 / FD, jj0 = r0 - ii0 * FD;
        int ii1 = r1 / FD, jj1 = r1 - ii1 * FD;
        const float* ob0 = outputs + ((size_t)b * (A_N * 25) + a0 * 25) * SD + r0;
        const float* ob1 = outputs + ((size_t)b * (A_N * 25) + a1 * 25) * SD + r1;
        float q00 = 0, q01 = 0, q02 = 0, q03 = 0, q04 = 0;
        float q10 = 0, q11 = 0, q12 = 0, q13 = 0, q14 = 0;
        if (act) {
            q00 = ob0[0]; q01 = ob0[SD]; q02 = ob0[2*SD]; q03 = ob0[3*SD]; q04 = ob0[4*SD];
            q10 = ob1[0]; q11 = ob1[SD]; q12 = ob1[2*SD]; q13 = ob1[3*SD]; q14 = ob1[4*SD];
        }

        // GT staging: wave 0, ballot-compaction (no LDS atomics)
        if (tid < 64) {
            bool v = false;
            float gtlx = 0, gtly = 0, gbrx = 0, gbry = 0, e = 0;
            if (tid < OD) {
                const float* t = targets + (b * OD + tid) * 5;
                float tx = t[0], ty = t[1], tw = t[2], th = t[3], tc = t[4];
                if (tx + ty + tw + th + tc > 0.0f) {
                    v = true;
                    float gx = tx * FD, gy = ty * FD, gw = tw * FD, gh = th * FD;
                    gtlx = gx - gw*0.5f; gtly = gy - gh*0.5f;
                    gbrx = gx + gw*0.5f; gbry = gy + gh*0.5f;
                    e = IGN_T * (gw * gh + 1e-12f);        // 0.6*dn
                }
            }
            unsigned long long bal = __ballot(v);
            if (v) {
                int k = __popcll(bal & ((1ull << tid) - 1ull));
                g_box[k] = make_float4(gtlx, gtly, gbrx, gbry);
                g_e[k] = e;
            }
            if (tid == 0) s_cnt = __popcll(bal);
        }
        __syncthreads();
        const int cnt = s_cnt;

        float base = 0.0f, corr = 0.0f;
        bool hot = false;
        if (act) {
            float aw0 = s_anc[2*a0] * FD, ah0 = s_anc[2*a0+1] * FD;
            float aw1 = s_anc[2*a1] * FD, ah1 = s_anc[2*a1+1] * FD;
            float px0 = sigm(q00) + (float)jj0, py0 = sigm(q01) + (float)ii0;
            float px1 = sigm(q10) + (float)jj1, py1 = sigm(q11) + (float)ii1;
            float pw0 = __expf(q02) * aw0, ph0 = __expf(q03) * ah0;
            float pw1 = __expf(q12) * aw1, ph1 = __expf(q13) * ah1;
            float tlx0 = px0 - pw0*0.5f, tly0 = py0 - ph0*0.5f;
            float brx0 = px0 + pw0*0.5f, bry0 = py0 + ph0*0.5f;
            float tlx1 = px1 - pw1*0.5f, tly1 = py1 - ph1*0.5f;
            float brx1 = px1 + pw1*0.5f, bry1 = py1 + ph1*0.5f;
            float f60 = IGN_T * (pw0 * ph0);               // 0.6*ar0
            float f61 = IGN_T * (pw1 * ph1);               // 0.6*ar1

            float dm0 = -1e30f, dm1 = -1e30f;
            for (int o = 0; o < cnt; ++o) {
                float4 bx = g_box[o];
                float e = g_e[o];
                float w0 = fmaxf(fminf(brx0, bx.z) - fmaxf(tlx0, bx.x), 0.0f);
                float h0 = fmaxf(fminf(bry0, bx.w) - fmaxf(tly0, bx.y), 0.0f);
                dm0 = fmaxf(dm0, fmaf((1.0f + IGN_T), w0 * h0, -(e + f60)));
                float w1 = fmaxf(fminf(brx1, bx.z) - fmaxf(tlx1, bx.x), 0.0f);
                float h1 = fmaxf(fminf(bry1, bx.w) - fmaxf(tly1, bx.y), 0.0f);
                dm1 = fmaxf(dm1, fmaf((1.0f + IGN_T), w1 * h1, -(e + f61)));
            }
            hot = (dm0 > 0.0f) || (dm1 > 0.0f);            // m > 0.6 (n_pos)
            float c0 = sigm(q04); c0 *= c0;
            float c1 = sigm(q14); c1 *= c1;
            if (dm0 >= 0.0f) corr += c0; else base += c0;  // m >= 0.6
            if (dm1 >= 0.0f) corr += c1; else base += c1;
        }

        unsigned long long bal = __ballot(hot);
        if ((tid & 63) == 0 && bal) atomicOr(&s_any, 1);

        #pragma unroll
        for (int off = 32; off > 0; off >>= 1) {
            base += __shfl_down(base, off);
            corr += __shfl_down(corr, off);
        }
        int lane = tid & 63, w = tid >> 6;
        if (lane == 0) { wb[w] = base; wc[w] = corr; }
        __syncthreads();
        blkBase = wb[0] + wb[1] + wb[2] + wb[3];
        blkCorr = wc[0] + wc[1] + wc[2] + wc[3];
        blkHot  = s_any;
    }

    // ---- cross-block combine: atomics only, last-block resolves ------------
    if (tid == 0) {
        atomicAdd(&d_pbase[b], blkBase);
        atomicAdd(&d_pcorr[b], blkCorr);
        if (blkHot) atomicOr(&d_pflag[b], 1);
        __threadfence();
        int prev = atomicAdd(&d_pdone[b], 1);
        if (prev == GXP) {                 // all GXP+1 blocks of batch b done
            __threadfence();
            float sb = atomicExch(&d_pbase[b], 0.0f);   // read + self-clean
            float sc = atomicExch(&d_pcorr[b], 0.0f);
            int   fl = atomicExch(&d_pflag[b], 0);
            atomicExch(&d_pdone[b], 0);
            float contrib = (sb + (fl ? 0.0f : sc)) * (1.0f / (float)BD);
            atomicAdd(&d_total, contrib);
            __threadfence();
            int od = atomicAdd(&d_done, 1);
            if (od == BD - 1) {            // all 32 batches resolved
                __threadfence();
                float tot = atomicExch(&d_total, 0.0f);
                atomicExch(&d_done, 0);
                out[0] = tot;
            }
        }
    }
}

extern "C" void kernel_launch(void* const* d_in, const int* in_sizes, int n_in,
                              void* d_out, int out_size, void* d_ws, size_t ws_size,
                              hipStream_t stream) {
    (void)in_sizes; (void)n_in; (void)out_size; (void)d_ws; (void)ws_size;
    // d_ws deliberately unused (256 MiB re-poison); no memset node either —
    // the globally-last block writes out[0] directly.
    k_main<<<dim3(GXP + 1, BD), 256, 0, stream>>>((const float*)d_in[0],
                                                  (const float*)d_in[1],
                                                  (const float*)d_in[2],
                                                  (float*)d_out);
}

// Round 3
// 78.848 us; speedup vs baseline: 1.4250x; 1.2185x over previous
//
#include <hip/hip_runtime.h>
#include <math.h>

#define A_N 5
#define NC 20
#define FD 38
#define SD (FD*FD)        // 1444
#define BD 32
#define OD 50
#define SA (SD*A_N)       // 7220
#define HALF (SA/2)       // 3610 — each pos-thread does p and p+HALF
#define GXP 15            // pos blocks per batch (15*256 = 3840 >= 3610)
#define IGN_T 0.6f
#define OBJ_S 5.0f

__device__ __forceinline__ float sigm(float x) { return 1.0f / (1.0f + __expf(-x)); }

// Module-scope scratch (zero-initialized at load; self-cleaning per launch).
// Cross-block protocol is FENCE-FREE: every shared word is touched ONLY by
// device-scope atomic RMW (performed at the memory-side coherence point), and
// producer->counter ordering is enforced by waiting for the producer atomics'
// own completion (s_waitcnt vmcnt(0) on their returned values) before issuing
// the pdone increment. __threadfence() (agent-scope L2 writeback on gfx950 —
// the suspected 20us fence-storm of round 2) is never used.
__device__ float d_pbase[BD];
__device__ float d_pcorr[BD];
__device__ int   d_pflag[BD];
__device__ int   d_pdone[BD];
__device__ float d_total;
__device__ int   d_done;

// grid (GXP+1, BD), 256 threads. blockIdx.x < GXP: noobj/ignore position pass,
// 2 positions/thread (dual-strand ILP). The loop only THRESHOLD-TESTS IoU:
//   m >= 0.6  <=>  dmax >= 0  where dmax = max_o fma(1.6, inter, -(e + 0.6*ar)).
// blockIdx.x == GXP: responsible-object terms. Speculative n_pos split: base
// always counts; corr counts iff n_pos==0 — resolved by the LAST block of the
// batch; the globally-last resolver writes out[0].
__global__ __launch_bounds__(256) void k_main(
    const float* __restrict__ outputs, const float* __restrict__ targets,
    const float* __restrict__ anchors, float* __restrict__ out)
{
    __shared__ float4 g_box[OD];              // (tlx, tly, brx, bry)
    __shared__ float  g_e[OD];                // pos: 0.6*(area+1e-12); resp: area+1e-12
    __shared__ float  s_anc[2 * A_N];
    __shared__ int    s_cnt, s_any;
    __shared__ int    s_key[OD];
    __shared__ float  wb[4], wc[4];

    const int b = blockIdx.y;
    const int tid = threadIdx.x;
    if (tid == 0) s_any = 0;
    if (tid < 2 * A_N) s_anc[tid] = anchors[tid];

    float blkBase = 0.0f, blkCorr = 0.0f;
    int   blkHot  = 0;

    if (blockIdx.x == GXP) {
        // ---- responsible-object block (1 per batch) ----
        if (tid == 0) s_cnt = 0;
        __syncthreads();
        float gx = 0, gy = 0, gw = 0, gh = 0;
        int ct = 0, key = -1;
        if (tid < OD) {
            const float* t = targets + (b * OD + tid) * 5;
            float tx = t[0], ty = t[1], tw = t[2], th = t[3], tc = t[4];
            if (tx + ty + tw + th + tc > 0.0f) {
                gx = tx * FD; gy = ty * FD; gw = tw * FD; gh = th * FD;
                float gtlx = gx - gw*0.5f, gtly = gy - gh*0.5f;
                float gbrx = gx + gw*0.5f, gbry = gy + gh*0.5f;
                int k = atomicAdd(&s_cnt, 1);
                g_box[k] = make_float4(gtlx, gtly, gbrx, gbry);
                g_e[k] = gw * gh + 1e-12f;     // plain den (resp path)
                int cx = (int)floorf(gtlx), cy = (int)floorf(gtly);
                int cell = min(max(cy * FD + cx, 0), SD - 1);
                int ci = cell / FD, cj = cell - ci * FD;
                float acx = (float)cj + 0.5f, acy = (float)ci + 0.5f;
                float areaB = gw * gh;
                float best = -1.0f; int bi = 0;
                for (int a = 0; a < A_N; ++a) {
                    float aw = s_anc[2*a] * FD, ah = s_anc[2*a+1] * FD;
                    float w = fmaxf(fminf(acx + aw*0.5f, gbrx) - fmaxf(acx - aw*0.5f, gtlx), 0.0f);
                    float h = fmaxf(fminf(acy + ah*0.5f, gbry) - fmaxf(acy - ah*0.5f, gtly), 0.0f);
                    float inter = w * h;
                    float iou = inter / (aw*ah + areaB - inter + 1e-12f);
                    if (iou > best) { best = iou; bi = a; }
                }
                key = bi * SD + cell;
                ct = (int)tc;
            }
        }
        if (tid < OD) s_key[tid] = key;
        __syncthreads();
        const int cnt = s_cnt;

        float rbase = 0.0f, rcorr = 0.0f;
        if (tid < OD && key >= 0) {
            int win = -1;                      // last duplicate wins == numpy
            #pragma unroll 10
            for (int o = 0; o < OD; ++o) win = (s_key[o] == key) ? o : win;
            if (win == tid) {
                int a = key / SD, cell = key - a * SD;
                int ci = cell / FD, cj = cell - ci * FD;
                const float* ob = outputs + ((size_t)b * (A_N * 25) + a * 25) * SD + cell;
                float o0 = ob[0], o1 = ob[SD], o2 = ob[2*SD], o3 = ob[3*SD], o4 = ob[4*SD];
                float aw = s_anc[2*a] * FD, ah = s_anc[2*a+1] * FD;
                float px = sigm(o0) + (float)cj;
                float py = sigm(o1) + (float)ci;
                float ew = __expf(o2), eh = __expf(o3);
                float pw = ew * aw, ph = eh * ah;
                float tlx = px - pw*0.5f, tly = py - ph*0.5f;
                float brx = px + pw*0.5f, bry = py + ph*0.5f;
                float ar = pw * ph;
                float bn = 0.0f, bd = 1.0f;
                for (int o = 0; o < cnt; ++o) {
                    float4 bx = g_box[o];
                    float w = fmaxf(fminf(brx, bx.z) - fmaxf(tlx, bx.x), 0.0f);
                    float h = fmaxf(fminf(bry, bx.w) - fmaxf(tly, bx.y), 0.0f);
                    float in = w * h, de = ar + g_e[o] - in;
                    if (in * bd > bn * de) { bn = in; bd = de; }
                }
                float mi = bn / bd;
                float conf = sigm(o4);
                float d = conf - mi;                   // iou loss, mask=OBJ_SCALE
                rbase += OBJ_S * OBJ_S * d * d;
                float c2 = conf * conf;                // undo pos-block noobj term
                if (bn >= IGN_T * bd) rcorr -= c2;
                else                  rbase -= c2;
                // box loss: pd = [sigm, sigm, exp, exp] (NO anchor scale on pd)
                float dx = gx - ((float)cj + 0.5f);
                float dy = gy - ((float)ci + 0.5f);
                float e0 = sigm(o0) - dx;
                float e1 = sigm(o1) - dy;
                float e2 = ew - gw / aw;
                float e3 = eh - gh / ah;
                rbase += e0*e0 + e1*e1 + e2*e2 + e3*e3;
                // class loss: ce = -log_softmax(softmax(x))[ct], register-lean.
                // pmax == 1/esum algebraically (bit-identical).
                const float* cb = ob + 5 * SD;
                float xmax = -INFINITY;
                #pragma unroll
                for (int k = 0; k < NC; ++k) xmax = fmaxf(xmax, cb[k * SD]);
                float esum = 0.0f;
                #pragma unroll
                for (int k = 0; k < NC; ++k) esum += __expf(cb[k * SD] - xmax);
                float inv = 1.0f / esum;
                float pmax = inv;
                float pct = __expf(cb[ct * SD] - xmax) * inv;
                float e2s = 0.0f;
                #pragma unroll
                for (int k = 0; k < NC; ++k)
                    e2s += __expf(__expf(cb[k * SD] - xmax) * inv - pmax);
                rbase += -(pct - (pmax + __logf(e2s)));
            }
        }
        #pragma unroll
        for (int off = 32; off > 0; off >>= 1) {
            rbase += __shfl_down(rbase, off);
            rcorr += __shfl_down(rcorr, off);
        }
        int lane = tid & 63, w = tid >> 6;
        if (lane == 0) { wb[w] = rbase; wc[w] = rcorr; }
        __syncthreads();
        blkBase = wb[0] + wb[1] + wb[2] + wb[3];
        blkCorr = wc[0] + wc[1] + wc[2] + wc[3];
        blkHot  = 0;
    } else {
        // ---- position blocks: dual-strand, threshold-test loop ----
        const int ix = blockIdx.x * 256 + tid;
        const bool act = (ix < HALF);
        const int p0 = ix, p1 = ix + HALF;
        int a0 = p0 / SD, r0 = p0 - a0 * SD;
        int a1 = p1 / SD, r1 = p1 - a1 * SD;
        int ii0 = r0 / FD, jj0 = r0 - ii0 * FD;
        int ii1 = r1 / FD, jj1 = r1 - ii1 * FD;
        const float* ob0 = outputs + ((size_t)b * (A_N * 25) + a0 * 25) * SD + r0;
        const float* ob1 = outputs + ((size_t)b * (A_N * 25) + a1 * 25) * SD + r1;
        float q00 = 0, q01 = 0, q02 = 0, q03 = 0, q04 = 0;
        float q10 = 0, q11 = 0, q12 = 0, q13 = 0, q14 = 0;
        if (act) {
            q00 = ob0[0]; q01 = ob0[SD]; q02 = ob0[2*SD]; q03 = ob0[3*SD]; q04 = ob0[4*SD];
            q10 = ob1[0]; q11 = ob1[SD]; q12 = ob1[2*SD]; q13 = ob1[3*SD]; q14 = ob1[4*SD];
        }

        // GT staging: wave 0, ballot-compaction (no LDS atomics)
        if (tid < 64) {
            bool v = false;
            float gtlx = 0, gtly = 0, gbrx = 0, gbry = 0, e = 0;
            if (tid < OD) {
                const float* t = targets + (b * OD + tid) * 5;
                float tx = t[0], ty = t[1], tw = t[2], th = t[3], tc = t[4];
                if (tx + ty + tw + th + tc > 0.0f) {
                    v = true;
                    float gx = tx * FD, gy = ty * FD, gw = tw * FD, gh = th * FD;
                    gtlx = gx - gw*0.5f; gtly = gy - gh*0.5f;
                    gbrx = gx + gw*0.5f; gbry = gy + gh*0.5f;
                    e = IGN_T * (gw * gh + 1e-12f);        // 0.6*dn
                }
            }
            unsigned long long bal = __ballot(v);
            if (v) {
                int k = __popcll(bal & ((1ull << tid) - 1ull));
                g_box[k] = make_float4(gtlx, gtly, gbrx, gbry);
                g_e[k] = e;
            }
            if (tid == 0) s_cnt = __popcll(bal);
        }
        __syncthreads();
        const int cnt = s_cnt;

        float base = 0.0f, corr = 0.0f;
        bool hot = false;
        if (act) {
            float aw0 = s_anc[2*a0] * FD, ah0 = s_anc[2*a0+1] * FD;
            float aw1 = s_anc[2*a1] * FD, ah1 = s_anc[2*a1+1] * FD;
            float px0 = sigm(q00) + (float)jj0, py0 = sigm(q01) + (float)ii0;
            float px1 = sigm(q10) + (float)jj1, py1 = sigm(q11) + (float)ii1;
            float pw0 = __expf(q02) * aw0, ph0 = __expf(q03) * ah0;
            float pw1 = __expf(q12) * aw1, ph1 = __expf(q13) * ah1;
            float tlx0 = px0 - pw0*0.5f, tly0 = py0 - ph0*0.5f;
            float brx0 = px0 + pw0*0.5f, bry0 = py0 + ph0*0.5f;
            float tlx1 = px1 - pw1*0.5f, tly1 = py1 - ph1*0.5f;
            float brx1 = px1 + pw1*0.5f, bry1 = py1 + ph1*0.5f;
            float f60 = IGN_T * (pw0 * ph0);               // 0.6*ar0
            float f61 = IGN_T * (pw1 * ph1);               // 0.6*ar1

            float dm0 = -1e30f, dm1 = -1e30f;
            for (int o = 0; o < cnt; ++o) {
                float4 bx = g_box[o];
                float e = g_e[o];
                float w0 = fmaxf(fminf(brx0, bx.z) - fmaxf(tlx0, bx.x), 0.0f);
                float h0 = fmaxf(fminf(bry0, bx.w) - fmaxf(tly0, bx.y), 0.0f);
                dm0 = fmaxf(dm0, fmaf((1.0f + IGN_T), w0 * h0, -(e + f60)));
                float w1 = fmaxf(fminf(brx1, bx.z) - fmaxf(tlx1, bx.x), 0.0f);
                float h1 = fmaxf(fminf(bry1, bx.w) - fmaxf(tly1, bx.y), 0.0f);
                dm1 = fmaxf(dm1, fmaf((1.0f + IGN_T), w1 * h1, -(e + f61)));
            }
            hot = (dm0 > 0.0f) || (dm1 > 0.0f);            // m > 0.6 (n_pos)
            float c0 = sigm(q04); c0 *= c0;
            float c1 = sigm(q14); c1 *= c1;
            if (dm0 >= 0.0f) corr += c0; else base += c0;  // m >= 0.6
            if (dm1 >= 0.0f) corr += c1; else base += c1;
        }

        unsigned long long bal = __ballot(hot);
        if ((tid & 63) == 0 && bal) atomicOr(&s_any, 1);

        #pragma unroll
        for (int off = 32; off > 0; off >>= 1) {
            base += __shfl_down(base, off);
            corr += __shfl_down(corr, off);
        }
        int lane = tid & 63, w = tid >> 6;
        if (lane == 0) { wb[w] = base; wc[w] = corr; }
        __syncthreads();
        blkBase = wb[0] + wb[1] + wb[2] + wb[3];
        blkCorr = wc[0] + wc[1] + wc[2] + wc[3];
        blkHot  = s_any;
    }

    // ---- cross-block combine: fence-free, atomic-RMW-only protocol ----------
    if (tid == 0) {
        float ob_ = atomicAdd(&d_pbase[b], blkBase);
        float oc_ = atomicAdd(&d_pcorr[b], blkCorr);
        int   of_ = blkHot ? atomicOr(&d_pflag[b], 1) : 0;
        // Keep returning forms live, then wait for THEIR completion at the
        // coherence point before announcing done. Cost: one round-trip (~us/512
        // blocks overlapped), not an L2 writeback.
        asm volatile("" :: "v"(ob_), "v"(oc_), "v"(of_));
        asm volatile("s_waitcnt vmcnt(0)" ::: "memory");
        int prev = atomicAdd(&d_pdone[b], 1);
        if (prev == GXP) {                 // all GXP+1 blocks of batch b arrived
            // Same-address RMW: every contributor's adds completed before its
            // pdone increment, so these exchanges see all contributions.
            float sb = atomicExch(&d_pbase[b], 0.0f);   // read + self-clean
            float sc = atomicExch(&d_pcorr[b], 0.0f);
            int   fl = atomicExch(&d_pflag[b], 0);
            atomicExch(&d_pdone[b], 0);    // safe: all of batch b already arrived
            float contrib = (sb + (fl ? 0.0f : sc)) * (1.0f / (float)BD);
            float ot_ = atomicAdd(&d_total, contrib);
            asm volatile("" :: "v"(ot_));
            asm volatile("s_waitcnt vmcnt(0)" ::: "memory");
            int od = atomicAdd(&d_done, 1);
            if (od == BD - 1) {            // all 32 batches resolved
                float tot = atomicExch(&d_total, 0.0f);
                int   z_  = atomicExch(&d_done, 0);
                asm volatile("" :: "v"(z_));
                out[0] = tot;
            }
        }
    }
}

extern "C" void kernel_launch(void* const* d_in, const int* in_sizes, int n_in,
                              void* d_out, int out_size, void* d_ws, size_t ws_size,
                              hipStream_t stream) {
    (void)in_sizes; (void)n_in; (void)out_size; (void)d_ws; (void)ws_size;
    // d_ws unused; its 256 MiB poison-fill is unconditional harness overhead
    // (~43 us) and sets the floor. Single kernel node, no memset node.
    k_main<<<dim3(GXP + 1, BD), 256, 0, stream>>>((const float*)d_in[0],
                                                  (const float*)d_in[1],
                                                  (const float*)d_in[2],
                                                  (float*)d_out);
}

// Round 4
// 76.904 us; speedup vs baseline: 1.4611x; 1.0253x over previous
//
#include <hip/hip_runtime.h>
#include <math.h>

#define A_N 5
#define NC 20
#define FD 38
#define SD (FD*FD)        // 1444
#define BD 32
#define OD 50
#define SA (SD*A_N)       // 7220
#define HALF (SA/2)       // 3610 — each pos-thread does p and p+HALF
#define GXP 15            // pos blocks per batch (15*256 = 3840 >= 3610)
#define IGN_T 0.6f
#define OBJ_S 5.0f

__device__ __forceinline__ float sigm(float x) { return 1.0f / (1.0f + __expf(-x)); }

// Module-scope scratch (zero-initialized at load; self-cleaning per launch).
// Fence-free protocol as in round 3, but CONTENTION-PADDED: round 3's tail
// (~20 us) was ~1800 device-scope RMWs from 512 blocks landing on FOUR cache
// lines (d_pbase/pcorr/pflag/pdone were 128B arrays). Now each batch owns one
// 256B line (32 lines in parallel, <=48 ops/line), the hot-flag is folded into
// the done counter (1 RMW saved/block), and the corr atomic is skipped when
// exactly 0.0f (true for most position blocks).
struct __align__(256) BatchSlot {
    float base;
    float corr;
    int   done;          // bits 0..7: arrival count; bits 8+: hot count
    int   pad[61];
};
struct __align__(256) PadF { float v; int pad[63]; };
struct __align__(256) PadI { int   v; int pad[63]; };
__device__ BatchSlot d_slot[BD];
__device__ PadF d_tot;
__device__ PadI d_fin;

// grid (GXP+1, BD), 256 threads. blockIdx.x < GXP: noobj/ignore position pass,
// 2 positions/thread (dual-strand ILP). The loop only THRESHOLD-TESTS IoU:
//   m >= 0.6  <=>  dmax >= 0  where dmax = max_o fma(1.6, inter, -(e + 0.6*ar)).
// blockIdx.x == GXP: responsible-object terms. Speculative n_pos split: base
// always counts; corr counts iff n_pos==0 — resolved by the LAST block of the
// batch; the globally-last resolver writes out[0].
__global__ __launch_bounds__(256) void k_main(
    const float* __restrict__ outputs, const float* __restrict__ targets,
    const float* __restrict__ anchors, float* __restrict__ out)
{
    __shared__ float4 g_box[OD];              // (tlx, tly, brx, bry)
    __shared__ float  g_e[OD];                // pos: 0.6*(area+1e-12); resp: area+1e-12
    __shared__ float  s_anc[2 * A_N];
    __shared__ int    s_cnt, s_any;
    __shared__ int    s_key[OD];
    __shared__ float  wb[4], wc[4];

    const int b = blockIdx.y;
    const int tid = threadIdx.x;
    if (tid == 0) s_any = 0;
    if (tid < 2 * A_N) s_anc[tid] = anchors[tid];

    float blkBase = 0.0f, blkCorr = 0.0f;
    int   blkHot  = 0;

    if (blockIdx.x == GXP) {
        // ---- responsible-object block (1 per batch) ----
        if (tid == 0) s_cnt = 0;
        __syncthreads();
        float gx = 0, gy = 0, gw = 0, gh = 0;
        int ct = 0, key = -1;
        if (tid < OD) {
            const float* t = targets + (b * OD + tid) * 5;
            float tx = t[0], ty = t[1], tw = t[2], th = t[3], tc = t[4];
            if (tx + ty + tw + th + tc > 0.0f) {
                gx = tx * FD; gy = ty * FD; gw = tw * FD; gh = th * FD;
                float gtlx = gx - gw*0.5f, gtly = gy - gh*0.5f;
                float gbrx = gx + gw*0.5f, gbry = gy + gh*0.5f;
                int k = atomicAdd(&s_cnt, 1);
                g_box[k] = make_float4(gtlx, gtly, gbrx, gbry);
                g_e[k] = gw * gh + 1e-12f;     // plain den (resp path)
                int cx = (int)floorf(gtlx), cy = (int)floorf(gtly);
                int cell = min(max(cy * FD + cx, 0), SD - 1);
                int ci = cell / FD, cj = cell - ci * FD;
                float acx = (float)cj + 0.5f, acy = (float)ci + 0.5f;
                float areaB = gw * gh;
                float best = -1.0f; int bi = 0;
                for (int a = 0; a < A_N; ++a) {
                    float aw = s_anc[2*a] * FD, ah = s_anc[2*a+1] * FD;
                    float w = fmaxf(fminf(acx + aw*0.5f, gbrx) - fmaxf(acx - aw*0.5f, gtlx), 0.0f);
                    float h = fmaxf(fminf(acy + ah*0.5f, gbry) - fmaxf(acy - ah*0.5f, gtly), 0.0f);
                    float inter = w * h;
                    float iou = inter / (aw*ah + areaB - inter + 1e-12f);
                    if (iou > best) { best = iou; bi = a; }
                }
                key = bi * SD + cell;
                ct = (int)tc;
            }
        }
        if (tid < OD) s_key[tid] = key;
        __syncthreads();
        const int cnt = s_cnt;

        float rbase = 0.0f, rcorr = 0.0f;
        if (tid < OD && key >= 0) {
            int win = -1;                      // last duplicate wins == numpy
            #pragma unroll 10
            for (int o = 0; o < OD; ++o) win = (s_key[o] == key) ? o : win;
            if (win == tid) {
                int a = key / SD, cell = key - a * SD;
                int ci = cell / FD, cj = cell - ci * FD;
                const float* ob = outputs + ((size_t)b * (A_N * 25) + a * 25) * SD + cell;
                float o0 = ob[0], o1 = ob[SD], o2 = ob[2*SD], o3 = ob[3*SD], o4 = ob[4*SD];
                float aw = s_anc[2*a] * FD, ah = s_anc[2*a+1] * FD;
                float px = sigm(o0) + (float)cj;
                float py = sigm(o1) + (float)ci;
                float ew = __expf(o2), eh = __expf(o3);
                float pw = ew * aw, ph = eh * ah;
                float tlx = px - pw*0.5f, tly = py - ph*0.5f;
                float brx = px + pw*0.5f, bry = py + ph*0.5f;
                float ar = pw * ph;
                float bn = 0.0f, bd = 1.0f;
                for (int o = 0; o < cnt; ++o) {
                    float4 bx = g_box[o];
                    float w = fmaxf(fminf(brx, bx.z) - fmaxf(tlx, bx.x), 0.0f);
                    float h = fmaxf(fminf(bry, bx.w) - fmaxf(tly, bx.y), 0.0f);
                    float in = w * h, de = ar + g_e[o] - in;
                    if (in * bd > bn * de) { bn = in; bd = de; }
                }
                float mi = bn / bd;
                float conf = sigm(o4);
                float d = conf - mi;                   // iou loss, mask=OBJ_SCALE
                rbase += OBJ_S * OBJ_S * d * d;
                float c2 = conf * conf;                // undo pos-block noobj term
                if (bn >= IGN_T * bd) rcorr -= c2;
                else                  rbase -= c2;
                // box loss: pd = [sigm, sigm, exp, exp] (NO anchor scale on pd)
                float dx = gx - ((float)cj + 0.5f);
                float dy = gy - ((float)ci + 0.5f);
                float e0 = sigm(o0) - dx;
                float e1 = sigm(o1) - dy;
                float e2 = ew - gw / aw;
                float e3 = eh - gh / ah;
                rbase += e0*e0 + e1*e1 + e2*e2 + e3*e3;
                // class loss: ce = -log_softmax(softmax(x))[ct], register-lean.
                // pmax == 1/esum algebraically (bit-identical).
                const float* cb = ob + 5 * SD;
                float xmax = -INFINITY;
                #pragma unroll
                for (int k = 0; k < NC; ++k) xmax = fmaxf(xmax, cb[k * SD]);
                float esum = 0.0f;
                #pragma unroll
                for (int k = 0; k < NC; ++k) esum += __expf(cb[k * SD] - xmax);
                float inv = 1.0f / esum;
                float pmax = inv;
                float pct = __expf(cb[ct * SD] - xmax) * inv;
                float e2s = 0.0f;
                #pragma unroll
                for (int k = 0; k < NC; ++k)
                    e2s += __expf(__expf(cb[k * SD] - xmax) * inv - pmax);
                rbase += -(pct - (pmax + __logf(e2s)));
            }
        }
        #pragma unroll
        for (int off = 32; off > 0; off >>= 1) {
            rbase += __shfl_down(rbase, off);
            rcorr += __shfl_down(rcorr, off);
        }
        int lane = tid & 63, w = tid >> 6;
        if (lane == 0) { wb[w] = rbase; wc[w] = rcorr; }
        __syncthreads();
        blkBase = wb[0] + wb[1] + wb[2] + wb[3];
        blkCorr = wc[0] + wc[1] + wc[2] + wc[3];
        blkHot  = 0;
    } else {
        // ---- position blocks: dual-strand, threshold-test loop ----
        const int ix = blockIdx.x * 256 + tid;
        const bool act = (ix < HALF);
        const int p0 = ix, p1 = ix + HALF;
        int a0 = p0 / SD, r0 = p0 - a0 * SD;
        int a1 = p1 / SD, r1 = p1 - a1 * SD;
        int ii0 = r0 / FD, jj0 = r0 - ii0 * FD;
        int ii1 = r1 / FD, jj1 = r1 - ii1 * FD;
        const float* ob0 = outputs + ((size_t)b * (A_N * 25) + a0 * 25) * SD + r0;
        const float* ob1 = outputs + ((size_t)b * (A_N * 25) + a1 * 25) * SD + r1;
        float q00 = 0, q01 = 0, q02 = 0, q03 = 0, q04 = 0;
        float q10 = 0, q11 = 0, q12 = 0, q13 = 0, q14 = 0;
        if (act) {
            q00 = ob0[0]; q01 = ob0[SD]; q02 = ob0[2*SD]; q03 = ob0[3*SD]; q04 = ob0[4*SD];
            q10 = ob1[0]; q11 = ob1[SD]; q12 = ob1[2*SD]; q13 = ob1[3*SD]; q14 = ob1[4*SD];
        }

        // GT staging: wave 0, ballot-compaction (no LDS atomics)
        if (tid < 64) {
            bool v = false;
            float gtlx = 0, gtly = 0, gbrx = 0, gbry = 0, e = 0;
            if (tid < OD) {
                const float* t = targets + (b * OD + tid) * 5;
                float tx = t[0], ty = t[1], tw = t[2], th = t[3], tc = t[4];
                if (tx + ty + tw + th + tc > 0.0f) {
                    v = true;
                    float gx = tx * FD, gy = ty * FD, gw = tw * FD, gh = th * FD;
                    gtlx = gx - gw*0.5f; gtly = gy - gh*0.5f;
                    gbrx = gx + gw*0.5f; gbry = gy + gh*0.5f;
                    e = IGN_T * (gw * gh + 1e-12f);        // 0.6*dn
                }
            }
            unsigned long long bal = __ballot(v);
            if (v) {
                int k = __popcll(bal & ((1ull << tid) - 1ull));
                g_box[k] = make_float4(gtlx, gtly, gbrx, gbry);
                g_e[k] = e;
            }
            if (tid == 0) s_cnt = __popcll(bal);
        }
        __syncthreads();
        const int cnt = s_cnt;

        float base = 0.0f, corr = 0.0f;
        bool hot = false;
        if (act) {
            float aw0 = s_anc[2*a0] * FD, ah0 = s_anc[2*a0+1] * FD;
            float aw1 = s_anc[2*a1] * FD, ah1 = s_anc[2*a1+1] * FD;
            float px0 = sigm(q00) + (float)jj0, py0 = sigm(q01) + (float)ii0;
            float px1 = sigm(q10) + (float)jj1, py1 = sigm(q11) + (float)ii1;
            float pw0 = __expf(q02) * aw0, ph0 = __expf(q03) * ah0;
            float pw1 = __expf(q12) * aw1, ph1 = __expf(q13) * ah1;
            float tlx0 = px0 - pw0*0.5f, tly0 = py0 - ph0*0.5f;
            float brx0 = px0 + pw0*0.5f, bry0 = py0 + ph0*0.5f;
            float tlx1 = px1 - pw1*0.5f, tly1 = py1 - ph1*0.5f;
            float brx1 = px1 + pw1*0.5f, bry1 = py1 + ph1*0.5f;
            float f60 = IGN_T * (pw0 * ph0);               // 0.6*ar0
            float f61 = IGN_T * (pw1 * ph1);               // 0.6*ar1

            float dm0 = -1e30f, dm1 = -1e30f;
            for (int o = 0; o < cnt; ++o) {
                float4 bx = g_box[o];
                float e = g_e[o];
                float w0 = fmaxf(fminf(brx0, bx.z) - fmaxf(tlx0, bx.x), 0.0f);
                float h0 = fmaxf(fminf(bry0, bx.w) - fmaxf(tly0, bx.y), 0.0f);
                dm0 = fmaxf(dm0, fmaf((1.0f + IGN_T), w0 * h0, -(e + f60)));
                float w1 = fmaxf(fminf(brx1, bx.z) - fmaxf(tlx1, bx.x), 0.0f);
                float h1 = fmaxf(fminf(bry1, bx.w) - fmaxf(tly1, bx.y), 0.0f);
                dm1 = fmaxf(dm1, fmaf((1.0f + IGN_T), w1 * h1, -(e + f61)));
            }
            hot = (dm0 > 0.0f) || (dm1 > 0.0f);            // m > 0.6 (n_pos)
            float c0 = sigm(q04); c0 *= c0;
            float c1 = sigm(q14); c1 *= c1;
            if (dm0 >= 0.0f) corr += c0; else base += c0;  // m >= 0.6
            if (dm1 >= 0.0f) corr += c1; else base += c1;
        }

        unsigned long long bal = __ballot(hot);
        if ((tid & 63) == 0 && bal) atomicOr(&s_any, 1);

        #pragma unroll
        for (int off = 32; off > 0; off >>= 1) {
            base += __shfl_down(base, off);
            corr += __shfl_down(corr, off);
        }
        int lane = tid & 63, w = tid >> 6;
        if (lane == 0) { wb[w] = base; wc[w] = corr; }
        __syncthreads();
        blkBase = wb[0] + wb[1] + wb[2] + wb[3];
        blkCorr = wc[0] + wc[1] + wc[2] + wc[3];
        blkHot  = s_any;
    }

    // ---- cross-block combine: fence-free, contention-padded -----------------
    if (tid == 0) {
        BatchSlot* S = &d_slot[b];
        float ob_ = atomicAdd(&S->base, blkBase);
        float oc_ = 0.0f;
        if (blkCorr != 0.0f) oc_ = atomicAdd(&S->corr, blkCorr); // usually skipped
        // Wait for the value-RMWs' own completion at the coherence point before
        // announcing arrival (fence-free ordering; all words share S's line).
        asm volatile("" :: "v"(ob_), "v"(oc_));
        asm volatile("s_waitcnt vmcnt(0)" ::: "memory");
        int prev = atomicAdd(&S->done, 1 + (blkHot ? 256 : 0));
        if ((prev & 0xFF) == GXP) {        // all GXP+1 blocks of batch b arrived
            int hotcnt = (prev >> 8) + (blkHot ? 1 : 0);
            float sb = atomicExch(&S->base, 0.0f);   // read + self-clean
            float sc = atomicExch(&S->corr, 0.0f);
            atomicExch(&S->done, 0);       // safe: all of batch b already arrived
            float contrib = (sb + (hotcnt ? 0.0f : sc)) * (1.0f / (float)BD);
            float ot_ = atomicAdd(&d_tot.v, contrib);
            asm volatile("" :: "v"(ot_));
            asm volatile("s_waitcnt vmcnt(0)" ::: "memory");
            int od = atomicAdd(&d_fin.v, 1);
            if (od == BD - 1) {            // all 32 batches resolved
                float tot = atomicExch(&d_tot.v, 0.0f);
                int   z_  = atomicExch(&d_fin.v, 0);
                asm volatile("" :: "v"(z_));
                out[0] = tot;
            }
        }
    }
}

extern "C" void kernel_launch(void* const* d_in, const int* in_sizes, int n_in,
                              void* d_out, int out_size, void* d_ws, size_t ws_size,
                              hipStream_t stream) {
    (void)in_sizes; (void)n_in; (void)out_size; (void)d_ws; (void)ws_size;
    // d_ws unused; its 256 MiB poison-fill is unconditional harness overhead
    // (~44 us) and, with ~10 us node overhead, sets a ~54 us floor.
    k_main<<<dim3(GXP + 1, BD), 256, 0, stream>>>((const float*)d_in[0],
                                                  (const float*)d_in[1],
                                                  (const float*)d_in[2],
                                                  (float*)d_out);
}

// Round 5
// 75.857 us; speedup vs baseline: 1.4812x; 1.0138x over previous
//
#include <hip/hip_runtime.h>
#include <math.h>

#define A_N 5
#define NC 20
#define FD 38
#define SD (FD*FD)        // 1444
#define BD 32
#define OD 50
#define SA (SD*A_N)       // 7220
#define HALF (SA/2)       // 3610 — each pos-thread does p and p+HALF
#define GXP 15            // pos blocks per batch (15*256 = 3840 >= 3610)
#define IGN_T 0.6f
#define OBJ_S 5.0f

__device__ __forceinline__ float sigm(float x) { return 1.0f / (1.0f + __expf(-x)); }

// Module-scope scratch (zero-initialized at load; self-cleaning per launch).
// Fence-free, contention-padded combine (round 4, validated absmax 0.0).
struct __align__(256) BatchSlot {
    float base;
    float corr;
    int   done;          // bits 0..7: arrival count; bits 8+: hot count
    int   pad[61];
};
struct __align__(256) PadF { float v; int pad[63]; };
struct __align__(256) PadI { int   v; int pad[63]; };
__device__ BatchSlot d_slot[BD];
__device__ PadF d_tot;
__device__ PadI d_fin;

// grid (GXP+1, BD), 256 threads. blockIdx.x < GXP: noobj/ignore position pass,
// 2 positions/thread (dual-strand ILP). Threshold-test form with HOISTED
// per-position threshold:  m >= 0.6  <=>  dm >= f6  where
//   dm = max_o fma(1.6, inter_o, -e_o),  e_o = 0.6*(area_o+1e-12),  f6 = 0.6*ar.
// blockIdx.x == GXP: responsible-object terms with EARLY channel prefetch
// (all 25 channel values issued before the winner scan — the winner scan is
// LDS-only and overlaps the scattered-load latency; round-4's version loaded
// them after winning, adding 1-2 dependent HBM rounds to the kernel tail).
__global__ __launch_bounds__(256) void k_main(
    const float* __restrict__ outputs, const float* __restrict__ targets,
    const float* __restrict__ anchors, float* __restrict__ out)
{
    __shared__ float4 g_box[OD];              // (tlx, tly, brx, bry)
    __shared__ float  g_e[OD];                // pos: 0.6*(area+1e-12); resp: area+1e-12
    __shared__ float  s_anc[2 * A_N];
    __shared__ int    s_cnt, s_any;
    __shared__ int    s_key[OD];
    __shared__ float  wb[4], wc[4];

    const int b = blockIdx.y;
    const int tid = threadIdx.x;
    if (tid == 0) s_any = 0;
    if (tid < 2 * A_N) s_anc[tid] = anchors[tid];

    float blkBase = 0.0f, blkCorr = 0.0f;
    int   blkHot  = 0;

    if (blockIdx.x == GXP) {
        // ---- responsible-object block (1 per batch) ----
        if (tid == 0) s_cnt = 0;
        __syncthreads();
        float gx = 0, gy = 0, gw = 0, gh = 0;
        int ct = 0, key = -1;
        float c5[25];                         // prefetched channel values
        if (tid < OD) {
            const float* t = targets + (b * OD + tid) * 5;   // round-1 loads
            float tx = t[0], ty = t[1], tw = t[2], th = t[3], tc = t[4];
            if (tx + ty + tw + th + tc > 0.0f) {
                gx = tx * FD; gy = ty * FD; gw = tw * FD; gh = th * FD;
                float gtlx = gx - gw*0.5f, gtly = gy - gh*0.5f;
                float gbrx = gx + gw*0.5f, gbry = gy + gh*0.5f;
                int k = atomicAdd(&s_cnt, 1);
                g_box[k] = make_float4(gtlx, gtly, gbrx, gbry);
                g_e[k] = gw * gh + 1e-12f;     // plain den (resp path)
                int cx = (int)floorf(gtlx), cy = (int)floorf(gtly);
                int cell = min(max(cy * FD + cx, 0), SD - 1);
                int ci = cell / FD, cj = cell - ci * FD;
                float acx = (float)cj + 0.5f, acy = (float)ci + 0.5f;
                float areaB = gw * gh;
                float best = -1.0f; int bi = 0;
                for (int a = 0; a < A_N; ++a) {
                    float aw = s_anc[2*a] * FD, ah = s_anc[2*a+1] * FD;
                    float w = fmaxf(fminf(acx + aw*0.5f, gbrx) - fmaxf(acx - aw*0.5f, gtlx), 0.0f);
                    float h = fmaxf(fminf(acy + ah*0.5f, gbry) - fmaxf(acy - ah*0.5f, gtly), 0.0f);
                    float inter = w * h;
                    float iou = inter / (aw*ah + areaB - inter + 1e-12f);
                    if (iou > best) { best = iou; bi = a; }
                }
                key = bi * SD + cell;
                ct = (int)tc;
                // round-2 loads: ALL 25 channels for this object's (anchor,cell),
                // issued NOW (before winner scan). Losers just discard them.
                const float* ob = outputs + ((size_t)b * (A_N * 25) + bi * 25) * SD + cell;
                #pragma unroll
                for (int k2 = 0; k2 < 25; ++k2) c5[k2] = ob[k2 * SD];
            }
        }
        if (tid < OD) s_key[tid] = key;
        __syncthreads();
        const int cnt = s_cnt;

        float rbase = 0.0f, rcorr = 0.0f;
        if (tid < OD && key >= 0) {
            int win = -1;                      // last duplicate wins == numpy
            #pragma unroll 10
            for (int o = 0; o < OD; ++o) win = (s_key[o] == key) ? o : win;
            if (win == tid) {
                int a = key / SD, cell = key - a * SD;
                int ci = cell / FD, cj = cell - ci * FD;
                float o0 = c5[0], o1 = c5[1], o2 = c5[2], o3 = c5[3], o4 = c5[4];
                float aw = s_anc[2*a] * FD, ah = s_anc[2*a+1] * FD;
                float px = sigm(o0) + (float)cj;
                float py = sigm(o1) + (float)ci;
                float ew = __expf(o2), eh = __expf(o3);
                float pw = ew * aw, ph = eh * ah;
                float tlx = px - pw*0.5f, tly = py - ph*0.5f;
                float brx = px + pw*0.5f, bry = py + ph*0.5f;
                float ar = pw * ph;
                float bn = 0.0f, bd = 1.0f;
                for (int o = 0; o < cnt; ++o) {
                    float4 bx = g_box[o];
                    float w = fmaxf(fminf(brx, bx.z) - fmaxf(tlx, bx.x), 0.0f);
                    float h = fmaxf(fminf(bry, bx.w) - fmaxf(tly, bx.y), 0.0f);
                    float in = w * h, de = ar + g_e[o] - in;
                    if (in * bd > bn * de) { bn = in; bd = de; }
                }
                float mi = bn / bd;
                float conf = sigm(o4);
                float d = conf - mi;                   // iou loss, mask=OBJ_SCALE
                rbase += OBJ_S * OBJ_S * d * d;
                float c2 = conf * conf;                // undo pos-block noobj term
                if (bn >= IGN_T * bd) rcorr -= c2;
                else                  rbase -= c2;
                // box loss: pd = [sigm, sigm, exp, exp] (NO anchor scale on pd)
                float dx = gx - ((float)cj + 0.5f);
                float dy = gy - ((float)ci + 0.5f);
                float e0 = sigm(o0) - dx;
                float e1 = sigm(o1) - dy;
                float e2 = ew - gw / aw;
                float e3 = eh - gh / ah;
                rbase += e0*e0 + e1*e1 + e2*e2 + e3*e3;
                // class loss: ce = -log_softmax(softmax(x))[ct], from registers.
                // pmax == 1/esum algebraically (bit-identical to r4's math; ct
                // selection is unrolled-compare, no dynamic register indexing).
                float xmax = -INFINITY;
                #pragma unroll
                for (int k = 0; k < NC; ++k) xmax = fmaxf(xmax, c5[5 + k]);
                float esum = 0.0f, xct = 0.0f;
                #pragma unroll
                for (int k = 0; k < NC; ++k) {
                    esum += __expf(c5[5 + k] - xmax);
                    if (k == ct) xct = c5[5 + k];
                }
                float inv = 1.0f / esum;
                float pmax = inv;
                float pct = __expf(xct - xmax) * inv;
                float e2s = 0.0f;
                #pragma unroll
                for (int k = 0; k < NC; ++k)
                    e2s += __expf(__expf(c5[5 + k] - xmax) * inv - pmax);
                rbase += -(pct - (pmax + __logf(e2s)));
            }
        }
        #pragma unroll
        for (int off = 32; off > 0; off >>= 1) {
            rbase += __shfl_down(rbase, off);
            rcorr += __shfl_down(rcorr, off);
        }
        int lane = tid & 63, w = tid >> 6;
        if (lane == 0) { wb[w] = rbase; wc[w] = rcorr; }
        __syncthreads();
        blkBase = wb[0] + wb[1] + wb[2] + wb[3];
        blkCorr = wc[0] + wc[1] + wc[2] + wc[3];
        blkHot  = 0;
    } else {
        // ---- position blocks: dual-strand, threshold-test loop ----
        const int ix = blockIdx.x * 256 + tid;
        const bool act = (ix < HALF);

        // GT staging loads FIRST (program order) so the barrier-gating targets
        // data is ahead of the 10 q-loads in the memory queue.
        float tx = 0, ty = 0, tw = 0, th = 0, tc = 0;
        if (tid < OD) {
            const float* t = targets + (b * OD + tid) * 5;
            tx = t[0]; ty = t[1]; tw = t[2]; th = t[3]; tc = t[4];
        }

        const int p0 = ix, p1 = ix + HALF;
        int a0 = p0 / SD, r0 = p0 - a0 * SD;
        int a1 = p1 / SD, r1 = p1 - a1 * SD;
        int ii0 = r0 / FD, jj0 = r0 - ii0 * FD;
        int ii1 = r1 / FD, jj1 = r1 - ii1 * FD;
        const float* ob0 = outputs + ((size_t)b * (A_N * 25) + a0 * 25) * SD + r0;
        const float* ob1 = outputs + ((size_t)b * (A_N * 25) + a1 * 25) * SD + r1;
        float q00 = 0, q01 = 0, q02 = 0, q03 = 0, q04 = 0;
        float q10 = 0, q11 = 0, q12 = 0, q13 = 0, q14 = 0;
        if (act) {
            q00 = ob0[0]; q01 = ob0[SD]; q02 = ob0[2*SD]; q03 = ob0[3*SD]; q04 = ob0[4*SD];
            q10 = ob1[0]; q11 = ob1[SD]; q12 = ob1[2*SD]; q13 = ob1[3*SD]; q14 = ob1[4*SD];
        }

        // GT staging: wave 0, ballot-compaction (no LDS atomics)
        if (tid < 64) {
            bool v = false;
            float gtlx = 0, gtly = 0, gbrx = 0, gbry = 0, e = 0;
            if (tid < OD && (tx + ty + tw + th + tc > 0.0f)) {
                v = true;
                float gx = tx * FD, gy = ty * FD, gw = tw * FD, gh = th * FD;
                gtlx = gx - gw*0.5f; gtly = gy - gh*0.5f;
                gbrx = gx + gw*0.5f; gbry = gy + gh*0.5f;
                e = IGN_T * (gw * gh + 1e-12f);        // 0.6*dn
            }
            unsigned long long bal = __ballot(v);
            if (v) {
                int k = __popcll(bal & ((1ull << tid) - 1ull));
                g_box[k] = make_float4(gtlx, gtly, gbrx, gbry);
                g_e[k] = e;
            }
            if (tid == 0) s_cnt = __popcll(bal);
        }
        __syncthreads();
        const int cnt = s_cnt;

        float base = 0.0f, corr = 0.0f;
        bool hot = false;
        if (act) {
            float aw0 = s_anc[2*a0] * FD, ah0 = s_anc[2*a0+1] * FD;
            float aw1 = s_anc[2*a1] * FD, ah1 = s_anc[2*a1+1] * FD;
            float px0 = sigm(q00) + (float)jj0, py0 = sigm(q01) + (float)ii0;
            float px1 = sigm(q10) + (float)jj1, py1 = sigm(q11) + (float)ii1;
            float pw0 = __expf(q02) * aw0, ph0 = __expf(q03) * ah0;
            float pw1 = __expf(q12) * aw1, ph1 = __expf(q13) * ah1;
            float tlx0 = px0 - pw0*0.5f, tly0 = py0 - ph0*0.5f;
            float brx0 = px0 + pw0*0.5f, bry0 = py0 + ph0*0.5f;
            float tlx1 = px1 - pw1*0.5f, tly1 = py1 - ph1*0.5f;
            float brx1 = px1 + pw1*0.5f, bry1 = py1 + ph1*0.5f;
            float f60 = IGN_T * (pw0 * ph0);               // hoisted threshold 0.6*ar0
            float f61 = IGN_T * (pw1 * ph1);               // hoisted threshold 0.6*ar1

            float dm0 = -1e30f, dm1 = -1e30f;
            for (int o = 0; o < cnt; ++o) {
                float4 bx = g_box[o];
                float e = g_e[o];
                float w0 = fmaxf(fminf(brx0, bx.z) - fmaxf(tlx0, bx.x), 0.0f);
                float h0 = fmaxf(fminf(bry0, bx.w) - fmaxf(tly0, bx.y), 0.0f);
                dm0 = fmaxf(dm0, fmaf((1.0f + IGN_T), w0 * h0, -e));
                float w1 = fmaxf(fminf(brx1, bx.z) - fmaxf(tlx1, bx.x), 0.0f);
                float h1 = fmaxf(fminf(bry1, bx.w) - fmaxf(tly1, bx.y), 0.0f);
                dm1 = fmaxf(dm1, fmaf((1.0f + IGN_T), w1 * h1, -e));
            }
            hot = (dm0 > f60) || (dm1 > f61);              // m > 0.6 (n_pos)
            float c0 = sigm(q04); c0 *= c0;
            float c1 = sigm(q14); c1 *= c1;
            if (dm0 >= f60) corr += c0; else base += c0;   // m >= 0.6
            if (dm1 >= f61) corr += c1; else base += c1;
        }

        unsigned long long bal = __ballot(hot);
        if ((tid & 63) == 0 && bal) atomicOr(&s_any, 1);

        #pragma unroll
        for (int off = 32; off > 0; off >>= 1) {
            base += __shfl_down(base, off);
            corr += __shfl_down(corr, off);
        }
        int lane = tid & 63, w = tid >> 6;
        if (lane == 0) { wb[w] = base; wc[w] = corr; }
        __syncthreads();
        blkBase = wb[0] + wb[1] + wb[2] + wb[3];
        blkCorr = wc[0] + wc[1] + wc[2] + wc[3];
        blkHot  = s_any;
    }

    // ---- cross-block combine: fence-free, contention-padded (r4, validated) --
    if (tid == 0) {
        BatchSlot* S = &d_slot[b];
        float ob_ = atomicAdd(&S->base, blkBase);
        float oc_ = 0.0f;
        if (blkCorr != 0.0f) oc_ = atomicAdd(&S->corr, blkCorr); // usually skipped
        asm volatile("" :: "v"(ob_), "v"(oc_));
        asm volatile("s_waitcnt vmcnt(0)" ::: "memory");
        int prev = atomicAdd(&S->done, 1 + (blkHot ? 256 : 0));
        if ((prev & 0xFF) == GXP) {        // all GXP+1 blocks of batch b arrived
            int hotcnt = (prev >> 8) + (blkHot ? 1 : 0);
            float sb = atomicExch(&S->base, 0.0f);   // read + self-clean
            float sc = atomicExch(&S->corr, 0.0f);
            atomicExch(&S->done, 0);       // safe: all of batch b already arrived
            float contrib = (sb + (hotcnt ? 0.0f : sc)) * (1.0f / (float)BD);
            float ot_ = atomicAdd(&d_tot.v, contrib);
            asm volatile("" :: "v"(ot_));
            asm volatile("s_waitcnt vmcnt(0)" ::: "memory");
            int od = atomicAdd(&d_fin.v, 1);
            if (od == BD - 1) {            // all 32 batches resolved
                float tot = atomicExch(&d_tot.v, 0.0f);
                int   z_  = atomicExch(&d_fin.v, 0);
                asm volatile("" :: "v"(z_));
                out[0] = tot;
            }
        }
    }
}

extern "C" void kernel_launch(void* const* d_in, const int* in_sizes, int n_in,
                              void* d_out, int out_size, void* d_ws, size_t ws_size,
                              hipStream_t stream) {
    (void)in_sizes; (void)n_in; (void)out_size; (void)d_ws; (void)ws_size;
    // d_ws unused; its 256 MiB poison-fill is unconditional harness overhead
    // (~44 us) and, with ~11 us node overhead, sets a ~54 us floor.
    k_main<<<dim3(GXP + 1, BD), 256, 0, stream>>>((const float*)d_in[0],
                                                  (const float*)d_in[1],
                                                  (const float*)d_in[2],
                                                  (float*)d_out);
}